// Round 7
// baseline (394.342 us; speedup 1.0000x reference)
//
#include <hip/hip_runtime.h>

// AlignmentMatrix: out[b,i,j] = sum_d body[b,i,d]*w3[d]*pun[b,j,d]
//                             + dot(body[b,i,:],w1) + dot(pun[b,j,:],w2)
// B=64, L=1024, D=128, fp32 in/out.
//
// R8b: single-barrier whole-K structure (R8 with the nontemporal-store type
// fixed: __builtin_nontemporal_store needs a clang ext_vector, not the
// HIP_vector_type float4).
//  - 128x128 tile, whole D=128 staged at once (body 32KB + pun 32KB LDS).
//  - ONE __syncthreads per kernel: stage(+rank-1 dots, shfl-reduced, published
//    to LDS pre-barrier) -> barrier -> 32 MFMAs/wave uninterrupted -> stores.
//  - all 16 data loads issued up front (full MLP, no barrier-blocked hoisting).
//  - single-bf16 cross term (validated R7, absmax well under tolerance).
//  - XCD batch-chunked bijective swizzle (4096 % 8 == 0): per-XCD working
//    set ~1 MB << 4 MB L2.
//  - NON-TEMPORAL f32x4 stores: keep the 268 MB write stream from evicting
//    the L2-resident read tiles.
//  - acc[2][4] = 32 VGPR; staging regs dead before MFMA phase -> no spill at
//    the __launch_bounds__(512,4) 128-VGPR cap; 2 blocks/CU.

#define LSEQ 1024
#define H2K  128

typedef __attribute__((ext_vector_type(8))) short bfrag;
typedef __attribute__((ext_vector_type(4))) float f32x4;

__device__ __forceinline__ short f2bf(float x) {
    unsigned u = __float_as_uint(x);
    unsigned r = (u + 0x7fff + ((u >> 16) & 1)) >> 16;   // RNE
    return (short)r;
}

__global__ __launch_bounds__(512, 4) void align_fused(
    const float* __restrict__ body, const float* __restrict__ pun,
    const float* __restrict__ w_u, float* __restrict__ out)
{
    // Fragment-order LDS: short index ((kc*8 + tile)*64 + lane)*8,
    // kc = 32-k chunk (0..3), tile = 16-row tile (0..7).
    __shared__ __align__(16) short Cb[16384];   // body*w3 bf16 (32 KB)
    __shared__ __align__(16) short Pb[16384];   // pun bf16     (32 KB)
    __shared__ float sb[128];                   // s_body for tile rows
    __shared__ float sp[128];                   // s_pun  for tile cols

    // XCD batch-chunked bijective swizzle (gridDim.x = B*64, divisible by 8)
    const int nwg = gridDim.x;
    const int bid = blockIdx.x;
    const int tid = (bid & 7) * (nwg >> 3) + (bid >> 3);
    const int bb = tid >> 6;                    // batch (64 blocks per batch)
    const int r6 = tid & 63;
    const int ti = (r6 >> 3) * 128;             // body rows (output rows)
    const int tj = (r6 & 7) * 128;              // pun rows  (output cols)

    const int t    = threadIdx.x;
    const int lane = t & 63;
    const int w    = t >> 6;                    // wave id 0..7

    // Staging map: thread t owns row srow (tile = w) and k-octet k8 of every
    // 32-k chunk, for both operands.
    const int srow = w * 16 + (lane & 15);
    const int k8   = lane >> 4;

    const float4* bp  = (const float4*)(body + (size_t)(bb * LSEQ + ti + srow) * H2K) + k8 * 2;
    const float4* pp  = (const float4*)(pun  + (size_t)(bb * LSEQ + tj + srow) * H2K) + k8 * 2;
    const float4* w1v = (const float4*)(w_u          ) + k8 * 2;
    const float4* w2v = (const float4*)(w_u +     H2K) + k8 * 2;
    const float4* w3v = (const float4*)(w_u + 2 * H2K) + k8 * 2;

    // ---- stage whole tile: loads, rank-1 dots, bf16 convert, ds_write ----
    float db = 0.f, dp = 0.f;
#pragma unroll
    for (int kc = 0; kc < 4; ++kc) {
        const float4 xb0 = bp[kc * 8],  xb1 = bp[kc * 8 + 1];
        const float4 yp0 = pp[kc * 8],  yp1 = pp[kc * 8 + 1];
        const float4 u10 = w1v[kc * 8], u11 = w1v[kc * 8 + 1];
        const float4 u20 = w2v[kc * 8], u21 = w2v[kc * 8 + 1];
        const float4 u30 = w3v[kc * 8], u31 = w3v[kc * 8 + 1];

        db += xb0.x * u10.x + xb0.y * u10.y + xb0.z * u10.z + xb0.w * u10.w
            + xb1.x * u11.x + xb1.y * u11.y + xb1.z * u11.z + xb1.w * u11.w;
        dp += yp0.x * u20.x + yp0.y * u20.y + yp0.z * u20.z + yp0.w * u20.w
            + yp1.x * u21.x + yp1.y * u21.y + yp1.z * u21.z + yp1.w * u21.w;

        bfrag fb, fp;
        fb[0] = f2bf(xb0.x * u30.x); fb[1] = f2bf(xb0.y * u30.y);
        fb[2] = f2bf(xb0.z * u30.z); fb[3] = f2bf(xb0.w * u30.w);
        fb[4] = f2bf(xb1.x * u31.x); fb[5] = f2bf(xb1.y * u31.y);
        fb[6] = f2bf(xb1.z * u31.z); fb[7] = f2bf(xb1.w * u31.w);
        fp[0] = f2bf(yp0.x); fp[1] = f2bf(yp0.y);
        fp[2] = f2bf(yp0.z); fp[3] = f2bf(yp0.w);
        fp[4] = f2bf(yp1.x); fp[5] = f2bf(yp1.y);
        fp[6] = f2bf(yp1.z); fp[7] = f2bf(yp1.w);
        *(bfrag*)&Cb[(kc * 512 + t) * 8] = fb;
        *(bfrag*)&Pb[(kc * 512 + t) * 8] = fp;
    }

    // rank-1 reduce across the 4 k-octet lanes; publish before the barrier
    db += __shfl_xor(db, 16); db += __shfl_xor(db, 32);
    dp += __shfl_xor(dp, 16); dp += __shfl_xor(dp, 32);
    if (k8 == 0) {                              // lanes 0..15: srow = w*16+lane
        sb[srow] = db;
        sp[srow] = dp;
    }

    __syncthreads();                            // the kernel's ONE barrier

    // ---- compute: 32 MFMAs / wave, uninterrupted ----
    // Wave covers 4 i-tiles (wrow) x 2 j-tiles (wcol).
    const int wrow = w >> 2;                    // 0..1 -> it = wrow*4 + ii
    const int wcol = w & 3;                     // 0..3 -> jt = wcol*2 + jj
    f32x4 acc[2][4] = {};                       // [jj][ii], 32 VGPR
#pragma unroll
    for (int kc = 0; kc < 4; ++kc) {
        bfrag ph[2], cb[4];
#pragma unroll
        for (int jj = 0; jj < 2; ++jj)
            ph[jj] = *(const bfrag*)&Pb[((kc * 8 + wcol * 2 + jj) * 64 + lane) * 8];
#pragma unroll
        for (int ii = 0; ii < 4; ++ii)
            cb[ii] = *(const bfrag*)&Cb[((kc * 8 + wrow * 4 + ii) * 64 + lane) * 8];
#pragma unroll
        for (int jj = 0; jj < 2; ++jj)
#pragma unroll
            for (int ii = 0; ii < 4; ++ii)
                acc[jj][ii] = __builtin_amdgcn_mfma_f32_16x16x32_bf16(
                    ph[jj], cb[ii], acc[jj][ii], 0, 0, 0);
    }

    // ---- epilogue: + s_body[i] + s_pun[j], non-temporal f32x4 stores ----
    // D (swapped operands): col = lane&15 -> body row i;
    //                       j = jt*16 + (lane>>4)*4 + reg  (verified R4-R7).
    const int qd = lane >> 4, ln = lane & 15;
#pragma unroll
    for (int jj = 0; jj < 2; ++jj) {
        const int jl = (wcol * 2 + jj) * 16 + qd * 4;     // local col of reg 0
        const f32x4 spv = *(const f32x4*)&sp[jl];
#pragma unroll
        for (int ii = 0; ii < 4; ++ii) {
            const int rl = (wrow * 4 + ii) * 16 + ln;     // local row
            const float sbv = sb[rl];
            const f32x4 a = acc[jj][ii];
            f32x4 r = { a[0] + sbv + spv[0], a[1] + sbv + spv[1],
                        a[2] + sbv + spv[2], a[3] + sbv + spv[3] };
            __builtin_nontemporal_store(
                r, (f32x4*)&out[(size_t)(bb * LSEQ + ti + rl) * LSEQ + tj + jl]);
        }
    }
}

extern "C" void kernel_launch(void* const* d_in, const int* in_sizes, int n_in,
                              void* d_out, int out_size, void* d_ws, size_t ws_size,
                              hipStream_t stream) {
    const float* body = (const float*)d_in[1];
    const float* pun  = (const float*)d_in[2];
    const float* w_u  = (const float*)d_in[3];
    float* out = (float*)d_out;
    const int B = in_sizes[1] / (LSEQ * H2K);

    dim3 g(B * 64, 1, 1);
    align_fused<<<g, 512, 0, stream>>>(body, pun, w_u, out);
}

// Round 8
// 392.033 us; speedup vs baseline: 1.0059x; 1.0059x over previous
//
#include <hip/hip_runtime.h>

// AlignmentMatrix: out[b,i,j] = sum_d body[b,i,d]*w3[d]*pun[b,j,d]
//                             + dot(body[b,i,:],w1) + dot(pun[b,j,:],w2)
// B=64, L=1024, D=128, fp32 in/out.
//
// R9: R8b with ONE change — non-temporal stores removed (plain f32x4 stores).
// R8b counters showed WRITE_SIZE 331 MB vs 268 ideal and 28% HBM: NT stores
// bypass L2 so the epilogue's 64-B row-segments hit HBM as partial lines.
// Cached stores let L2 merge neighboring waves' segments into full lines.
//  - 128x128 tile, whole D=128 staged at once (body 32KB + pun 32KB LDS).
//  - ONE __syncthreads per kernel: stage(+rank-1 dots, shfl-reduced, published
//    to LDS pre-barrier) -> barrier -> 32 MFMAs/wave uninterrupted -> stores.
//  - single-bf16 cross term (validated R7/R8b, absmax under tolerance).
//  - XCD batch-chunked bijective swizzle (4096 % 8 == 0).
//  - acc[2][4]; VGPR=56 measured; 2 blocks/CU (LDS-capped).

#define LSEQ 1024
#define H2K  128

typedef __attribute__((ext_vector_type(8))) short bfrag;
typedef __attribute__((ext_vector_type(4))) float f32x4;

__device__ __forceinline__ short f2bf(float x) {
    unsigned u = __float_as_uint(x);
    unsigned r = (u + 0x7fff + ((u >> 16) & 1)) >> 16;   // RNE
    return (short)r;
}

__global__ __launch_bounds__(512, 4) void align_fused(
    const float* __restrict__ body, const float* __restrict__ pun,
    const float* __restrict__ w_u, float* __restrict__ out)
{
    // Fragment-order LDS: short index ((kc*8 + tile)*64 + lane)*8,
    // kc = 32-k chunk (0..3), tile = 16-row tile (0..7).
    __shared__ __align__(16) short Cb[16384];   // body*w3 bf16 (32 KB)
    __shared__ __align__(16) short Pb[16384];   // pun bf16     (32 KB)
    __shared__ float sb[128];                   // s_body for tile rows
    __shared__ float sp[128];                   // s_pun  for tile cols

    // XCD batch-chunked bijective swizzle (gridDim.x = B*64, divisible by 8)
    const int nwg = gridDim.x;
    const int bid = blockIdx.x;
    const int tid = (bid & 7) * (nwg >> 3) + (bid >> 3);
    const int bb = tid >> 6;                    // batch (64 blocks per batch)
    const int r6 = tid & 63;
    const int ti = (r6 >> 3) * 128;             // body rows (output rows)
    const int tj = (r6 & 7) * 128;              // pun rows  (output cols)

    const int t    = threadIdx.x;
    const int lane = t & 63;
    const int w    = t >> 6;                    // wave id 0..7

    // Staging map: thread t owns row srow (tile = w) and k-octet k8 of every
    // 32-k chunk, for both operands.
    const int srow = w * 16 + (lane & 15);
    const int k8   = lane >> 4;

    const float4* bp  = (const float4*)(body + (size_t)(bb * LSEQ + ti + srow) * H2K) + k8 * 2;
    const float4* pp  = (const float4*)(pun  + (size_t)(bb * LSEQ + tj + srow) * H2K) + k8 * 2;
    const float4* w1v = (const float4*)(w_u          ) + k8 * 2;
    const float4* w2v = (const float4*)(w_u +     H2K) + k8 * 2;
    const float4* w3v = (const float4*)(w_u + 2 * H2K) + k8 * 2;

    // ---- stage whole tile: loads, rank-1 dots, bf16 convert, ds_write ----
    float db = 0.f, dp = 0.f;
#pragma unroll
    for (int kc = 0; kc < 4; ++kc) {
        const float4 xb0 = bp[kc * 8],  xb1 = bp[kc * 8 + 1];
        const float4 yp0 = pp[kc * 8],  yp1 = pp[kc * 8 + 1];
        const float4 u10 = w1v[kc * 8], u11 = w1v[kc * 8 + 1];
        const float4 u20 = w2v[kc * 8], u21 = w2v[kc * 8 + 1];
        const float4 u30 = w3v[kc * 8], u31 = w3v[kc * 8 + 1];

        db += xb0.x * u10.x + xb0.y * u10.y + xb0.z * u10.z + xb0.w * u10.w
            + xb1.x * u11.x + xb1.y * u11.y + xb1.z * u11.z + xb1.w * u11.w;
        dp += yp0.x * u20.x + yp0.y * u20.y + yp0.z * u20.z + yp0.w * u20.w
            + yp1.x * u21.x + yp1.y * u21.y + yp1.z * u21.z + yp1.w * u21.w;

        bfrag fb, fp;
        fb[0] = f2bf(xb0.x * u30.x); fb[1] = f2bf(xb0.y * u30.y);
        fb[2] = f2bf(xb0.z * u30.z); fb[3] = f2bf(xb0.w * u30.w);
        fb[4] = f2bf(xb1.x * u31.x); fb[5] = f2bf(xb1.y * u31.y);
        fb[6] = f2bf(xb1.z * u31.z); fb[7] = f2bf(xb1.w * u31.w);
        fp[0] = f2bf(yp0.x); fp[1] = f2bf(yp0.y);
        fp[2] = f2bf(yp0.z); fp[3] = f2bf(yp0.w);
        fp[4] = f2bf(yp1.x); fp[5] = f2bf(yp1.y);
        fp[6] = f2bf(yp1.z); fp[7] = f2bf(yp1.w);
        *(bfrag*)&Cb[(kc * 512 + t) * 8] = fb;
        *(bfrag*)&Pb[(kc * 512 + t) * 8] = fp;
    }

    // rank-1 reduce across the 4 k-octet lanes; publish before the barrier
    db += __shfl_xor(db, 16); db += __shfl_xor(db, 32);
    dp += __shfl_xor(dp, 16); dp += __shfl_xor(dp, 32);
    if (k8 == 0) {                              // lanes 0..15: srow = w*16+lane
        sb[srow] = db;
        sp[srow] = dp;
    }

    __syncthreads();                            // the kernel's ONE barrier

    // ---- compute: 32 MFMAs / wave, uninterrupted ----
    // Wave covers 4 i-tiles (wrow) x 2 j-tiles (wcol).
    const int wrow = w >> 2;                    // 0..1 -> it = wrow*4 + ii
    const int wcol = w & 3;                     // 0..3 -> jt = wcol*2 + jj
    f32x4 acc[2][4] = {};                       // [jj][ii], 32 VGPR
#pragma unroll
    for (int kc = 0; kc < 4; ++kc) {
        bfrag ph[2], cb[4];
#pragma unroll
        for (int jj = 0; jj < 2; ++jj)
            ph[jj] = *(const bfrag*)&Pb[((kc * 8 + wcol * 2 + jj) * 64 + lane) * 8];
#pragma unroll
        for (int ii = 0; ii < 4; ++ii)
            cb[ii] = *(const bfrag*)&Cb[((kc * 8 + wrow * 4 + ii) * 64 + lane) * 8];
#pragma unroll
        for (int jj = 0; jj < 2; ++jj)
#pragma unroll
            for (int ii = 0; ii < 4; ++ii)
                acc[jj][ii] = __builtin_amdgcn_mfma_f32_16x16x32_bf16(
                    ph[jj], cb[ii], acc[jj][ii], 0, 0, 0);
    }

    // ---- epilogue: + s_body[i] + s_pun[j], plain f32x4 stores ----
    // D (swapped operands): col = lane&15 -> body row i;
    //                       j = jt*16 + (lane>>4)*4 + reg  (verified R4-R8).
    const int qd = lane >> 4, ln = lane & 15;
#pragma unroll
    for (int jj = 0; jj < 2; ++jj) {
        const int jl = (wcol * 2 + jj) * 16 + qd * 4;     // local col of reg 0
        const f32x4 spv = *(const f32x4*)&sp[jl];
#pragma unroll
        for (int ii = 0; ii < 4; ++ii) {
            const int rl = (wrow * 4 + ii) * 16 + ln;     // local row
            const float sbv = sb[rl];
            const f32x4 a = acc[jj][ii];
            f32x4 r = { a[0] + sbv + spv[0], a[1] + sbv + spv[1],
                        a[2] + sbv + spv[2], a[3] + sbv + spv[3] };
            *(f32x4*)&out[(size_t)(bb * LSEQ + ti + rl) * LSEQ + tj + jl] = r;
        }
    }
}

extern "C" void kernel_launch(void* const* d_in, const int* in_sizes, int n_in,
                              void* d_out, int out_size, void* d_ws, size_t ws_size,
                              hipStream_t stream) {
    const float* body = (const float*)d_in[1];
    const float* pun  = (const float*)d_in[2];
    const float* w_u  = (const float*)d_in[3];
    float* out = (float*)d_out;
    const int B = in_sizes[1] / (LSEQ * H2K);

    dim3 g(B * 64, 1, 1);
    align_fused<<<g, 512, 0, stream>>>(body, pun, w_u, out);
}